// Round 3
// baseline (527.976 us; speedup 1.0000x reference)
//
#include <hip/hip_runtime.h>
#include <stdint.h>

#define NN     6258
#define IMG_N  1600
#define CNN_N  4608
#define OUT_N  50
#define BATCH  64
#define G0SZ   1650
#define G1SZ   4608
#define IMGW   40
#define NPATCH 12

// ---------------- threefry2x32-20, exactly as jax/_src/prng.py ----------------
__host__ __device__ inline void tf2x32(uint32_t k0, uint32_t k1,
                                       uint32_t x0, uint32_t x1,
                                       uint32_t& o0, uint32_t& o1) {
    uint32_t ks[3] = {k0, k1, k0 ^ k1 ^ 0x1BD11BDAu};
    const int rotA[4] = {13, 15, 26, 6};
    const int rotB[4] = {17, 29, 16, 24};
    x0 += ks[0];
    x1 += ks[1];
#pragma unroll
    for (int i = 0; i < 5; ++i) {
        const int* rot = (i & 1) ? rotB : rotA;
#pragma unroll
        for (int j = 0; j < 4; ++j) {
            x0 += x1;
            x1 = (x1 << rot[j]) | (x1 >> (32 - rot[j]));
            x1 ^= x0;
        }
        x0 += ks[(i + 1) % 3];
        x1 += ks[(i + 2) % 3] + (uint32_t)(i + 1);
    }
    o0 = x0;
    o1 = x1;
}

// jax.random.uniform(...)*2-1, partitionable threefry (default since JAX 0.4.36):
// bits[j] = xor-fold of threefry(key, (0, j)).
__device__ inline float jax_uniform_pm1(uint32_t k0, uint32_t k1, uint32_t j) {
    uint32_t o0, o1;
    tf2x32(k0, k1, 0u, j, o0, o1);
    uint32_t bits = o0 ^ o1;
    float f = __uint_as_float((bits >> 9) | 0x3f800000u); // [1,2)
    return (f - 1.0f) * 2.0f - 1.0f;                      // [-1,1)
}

// XLA's f32 tanh rational approximation, non-contracted f32 ops.
__device__ inline float tanh_xla_f32(float x) {
    if (fabsf(x) < 0.0004f) return x;
    float xc = fminf(fmaxf(x, -9.0f), 9.0f);
    float x2 = __fmul_rn(xc, xc);
    float num = -2.76076847742355e-16f;
    num = __fadd_rn(__fmul_rn(num, x2), 2.00018790482477e-13f);
    num = __fadd_rn(__fmul_rn(num, x2), -8.60467152213735e-11f);
    num = __fadd_rn(__fmul_rn(num, x2), 5.12229709037114e-08f);
    num = __fadd_rn(__fmul_rn(num, x2), 1.48572235717979e-05f);
    num = __fadd_rn(__fmul_rn(num, x2), 6.37261928875436e-04f);
    num = __fadd_rn(__fmul_rn(num, x2), 4.89352455891786e-03f);
    num = __fmul_rn(num, xc);
    float den = 1.19825839466702e-06f;
    den = __fadd_rn(__fmul_rn(den, x2), 1.18534705686654e-04f);
    den = __fadd_rn(__fmul_rn(den, x2), 2.26843463243900e-03f);
    den = __fadd_rn(__fmul_rn(den, x2), 4.89352518554385e-03f);
    return __fdiv_rn(num, den);
}

__device__ inline float gibbs_decide(double acc, float h, float u) {
    float I32 = (float)(acc + (double)h);
    float t = tanh_xla_f32(I32);
    float d = __fadd_rn(t, -u);
    return (d > 0.0f) ? 1.0f : ((d < 0.0f) ? -1.0f : 0.0f);
}

// mt layout: [node][b], node-major, 64 floats per node (coalesced across lanes).
__global__ __launch_bounds__(256) void t_in(const float* __restrict__ src,
                                            float* __restrict__ dst) {
    int tid = blockIdx.x * 256 + (int)threadIdx.x;
    if (tid < NN * BATCH) {
        int node = tid >> 6, b = tid & 63;
        dst[tid] = src[(size_t)b * NN + node];
    }
}

__global__ __launch_bounds__(256) void t_out(const float* __restrict__ src,
                                             float* __restrict__ dst) {
    int tid = blockIdx.x * 256 + (int)threadIdx.x;
    if (tid < NN * BATCH) {
        int b = tid / NN, node = tid - b * NN;  // node fast -> write coalesced
        dst[tid] = src[node * 64 + b];
    }
}

// ---------------- group0: img nodes (blocks 0..399) + out nodes (blocks 400..449) ----
__global__ __launch_bounds__(256) void g0_kernel(float* __restrict__ mt,
                                                 const float* __restrict__ J,
                                                 const float* __restrict__ H,
                                                 uint32_t k0, uint32_t k1) {
    __shared__ double red[4][64];
    int blk = blockIdx.x;
    if (blk < 400) {
        int tid = blk * 256 + (int)threadIdx.x;  // [0, 102400)
        int g = tid >> 6;                        // pixel 0..1599 (wave-uniform)
        int b = tid & 63;                        // lane = batch
        int r = g / IMGW, c = g % IMGW;
        int pr_lo = (r >= 4) ? (r - 2) / 3 : 0;
        int pr_hi = r / 3; if (pr_hi > NPATCH - 1) pr_hi = NPATCH - 1;
        int pc_lo = (c >= 4) ? (c - 2) / 3 : 0;
        int pc_hi = c / 3; if (pc_hi > NPATCH - 1) pc_hi = NPATCH - 1;
        const float* Jrow = J + (size_t)g * NN;
        double acc = 0.0;
        for (int pr = pr_lo; pr <= pr_hi; ++pr) {
            for (int pc = pc_lo; pc <= pc_hi; ++pc) {
                int base = IMG_N + pr * NPATCH + pc;
#pragma unroll
                for (int f = 0; f < 32; ++f) {
                    int col = base + f * 144;
                    acc += (double)Jrow[col] * (double)mt[col * 64 + b];
                }
            }
        }
        float u = jax_uniform_pm1(k0, k1, (uint32_t)(b * G0SZ + g));
        mt[g * 64 + b] = gibbs_decide(acc, H[g], u);
    } else {
        int o = blk - 400;                        // out node 0..49
        int w = (int)threadIdx.x >> 6;            // wave 0..3: k-chunk
        int lane = (int)threadIdx.x & 63;         // lane = batch
        const float* Jrow = J + (size_t)(IMG_N + CNN_N + o) * NN + IMG_N;
        double acc = 0.0;
        int k0i = w * 1152, k1i = k0i + 1152;
#pragma unroll 4
        for (int k = k0i; k < k1i; ++k)
            acc += (double)Jrow[k] * (double)mt[(IMG_N + k) * 64 + lane];
        red[w][lane] = acc;
        __syncthreads();
        if (w == 0) {
            double a = ((red[0][lane] + red[1][lane]) + red[2][lane]) + red[3][lane];
            float u = jax_uniform_pm1(k0, k1, (uint32_t)(lane * G0SZ + IMG_N + o));
            mt[(IMG_N + CNN_N + o) * 64 + lane] =
                gibbs_decide(a, H[IMG_N + CNN_N + o], u);
        }
    }
}

// ---------------- group1: cnn nodes, wave per cnode, lane = batch ----------------
__global__ __launch_bounds__(256) void g1_kernel(float* __restrict__ mt,
                                                 const float* __restrict__ J,
                                                 const float* __restrict__ H,
                                                 uint32_t k0, uint32_t k1) {
    int tid = blockIdx.x * 256 + (int)threadIdx.x;  // [0, 294912)
    int cnode = tid >> 6;  // 0..4607 (wave-uniform)
    int b = tid & 63;      // lane = batch
    int p = cnode % 144;
    int pr = p / NPATCH, pc = p % NPATCH;
    int r0 = pr * 3, c0 = pc * 3;
    const float* Jrow = J + (size_t)(IMG_N + cnode) * NN;
    double acc = 0.0;
#pragma unroll
    for (int a = 0; a < 5; ++a) {
        int rowbase = (r0 + a) * IMGW + c0;
#pragma unroll
        for (int bb = 0; bb < 5; ++bb) {
            int pix = rowbase + bb;
            acc += (double)Jrow[pix] * (double)mt[pix * 64 + b];
        }
    }
    const float* Jo = Jrow + IMG_N + CNN_N;
#pragma unroll 10
    for (int o = 0; o < OUT_N; ++o)
        acc += (double)Jo[o] * (double)mt[(IMG_N + CNN_N + o) * 64 + b];
    float u = jax_uniform_pm1(k0, k1, (uint32_t)(b * G1SZ + cnode));
    mt[(IMG_N + cnode) * 64 + b] = gibbs_decide(acc, H[IMG_N + cnode], u);
}

extern "C" void kernel_launch(void* const* d_in, const int* in_sizes, int n_in,
                              void* d_out, int out_size, void* d_ws, size_t ws_size,
                              hipStream_t stream) {
    const float* m_in = (const float*)d_in[0];
    const float* J    = (const float*)d_in[1];
    const float* H    = (const float*)d_in[2];
    float* m_out = (float*)d_out;
    float* mt    = (float*)d_ws;  // [NN][64] transposed spins

    const int TN = (NN * BATCH + 255) / 256;  // 1565
    t_in<<<TN, 256, 0, stream>>>(m_in, mt);

    // partitionable key chain: keys = split(key(1),4): keys[i]=threefry((0,1),(0,i))
    uint32_t K[4][2];
    for (int i = 0; i < 4; ++i)
        tf2x32(0u, 1u, 0u, (uint32_t)i, K[i][0], K[i][1]);

    for (int s = 0; s < 4; ++s) {
        uint32_t k0a, k0b, k1a, k1b;
        tf2x32(K[s][0], K[s][1], 0u, 0u, k0a, k0b);  // k0 = split(...)[0]
        tf2x32(K[s][0], K[s][1], 0u, 1u, k1a, k1b);  // k1 = split(...)[1]
        g0_kernel<<<450, 256, 0, stream>>>(mt, J, H, k0a, k0b);
        g1_kernel<<<1152, 256, 0, stream>>>(mt, J, H, k1a, k1b);
    }

    t_out<<<TN, 256, 0, stream>>>(mt, m_out);
}

// Round 4
// 380.769 us; speedup vs baseline: 1.3866x; 1.3866x over previous
//
#include <hip/hip_runtime.h>
#include <stdint.h>

#define NN     6258
#define IMG_N  1600
#define CNN_N  4608
#define OUT_N  50
#define BATCH  64
#define G0SZ   1650
#define G1SZ   4608
#define IMGW   40
#define NPATCH 12

// ---------------- threefry2x32-20, exactly as jax/_src/prng.py ----------------
__host__ __device__ inline void tf2x32(uint32_t k0, uint32_t k1,
                                       uint32_t x0, uint32_t x1,
                                       uint32_t& o0, uint32_t& o1) {
    uint32_t ks[3] = {k0, k1, k0 ^ k1 ^ 0x1BD11BDAu};
    const int rotA[4] = {13, 15, 26, 6};
    const int rotB[4] = {17, 29, 16, 24};
    x0 += ks[0];
    x1 += ks[1];
#pragma unroll
    for (int i = 0; i < 5; ++i) {
        const int* rot = (i & 1) ? rotB : rotA;
#pragma unroll
        for (int j = 0; j < 4; ++j) {
            x0 += x1;
            x1 = (x1 << rot[j]) | (x1 >> (32 - rot[j]));
            x1 ^= x0;
        }
        x0 += ks[(i + 1) % 3];
        x1 += ks[(i + 2) % 3] + (uint32_t)(i + 1);
    }
    o0 = x0;
    o1 = x1;
}

// jax.random.uniform(...)*2-1, partitionable threefry: bits[j] = xor-fold of
// threefry(key, (0, j)).
__device__ inline float jax_uniform_pm1(uint32_t k0, uint32_t k1, uint32_t j) {
    uint32_t o0, o1;
    tf2x32(k0, k1, 0u, j, o0, o1);
    uint32_t bits = o0 ^ o1;
    float f = __uint_as_float((bits >> 9) | 0x3f800000u); // [1,2)
    return (f - 1.0f) * 2.0f - 1.0f;                      // [-1,1)
}

// XLA's f32 tanh rational approximation, non-contracted f32 ops.
__device__ inline float tanh_xla_f32(float x) {
    if (fabsf(x) < 0.0004f) return x;
    float xc = fminf(fmaxf(x, -9.0f), 9.0f);
    float x2 = __fmul_rn(xc, xc);
    float num = -2.76076847742355e-16f;
    num = __fadd_rn(__fmul_rn(num, x2), 2.00018790482477e-13f);
    num = __fadd_rn(__fmul_rn(num, x2), -8.60467152213735e-11f);
    num = __fadd_rn(__fmul_rn(num, x2), 5.12229709037114e-08f);
    num = __fadd_rn(__fmul_rn(num, x2), 1.48572235717979e-05f);
    num = __fadd_rn(__fmul_rn(num, x2), 6.37261928875436e-04f);
    num = __fadd_rn(__fmul_rn(num, x2), 4.89352455891786e-03f);
    num = __fmul_rn(num, xc);
    float den = 1.19825839466702e-06f;
    den = __fadd_rn(__fmul_rn(den, x2), 1.18534705686654e-04f);
    den = __fadd_rn(__fmul_rn(den, x2), 2.26843463243900e-03f);
    den = __fadd_rn(__fmul_rn(den, x2), 4.89352518554385e-03f);
    return __fdiv_rn(num, den);
}

__device__ inline float gibbs_decide(double acc, float h, float u) {
    float I32 = (float)(acc + (double)h);
    float t = tanh_xla_f32(I32);
    float d = __fadd_rn(t, -u);
    return (d > 0.0f) ? 1.0f : ((d < 0.0f) ? -1.0f : 0.0f);
}

// J_CNN closure: J_CNN[f][pos] lives (bitwise) at J row of cnn node f*144
// (patch 0), col a*40+bb  (pos = a*5+bb).  ~160 hot cache lines total.
__device__ __forceinline__ float jcnn(const float* __restrict__ J, int f, int pos) {
    int a = pos / 5, bb = pos % 5;
    return J[(size_t)(IMG_N + f * 144) * NN + a * IMGW + bb];
}

// mt layout: [node][b] — 64 floats (256 B) per node, lane = batch.
__global__ __launch_bounds__(256) void t_in(const float* __restrict__ src,
                                            float* __restrict__ dst) {
    int tid = blockIdx.x * 256 + (int)threadIdx.x;
    if (tid < NN * BATCH) {
        int node = tid >> 6, b = tid & 63;
        dst[tid] = src[(size_t)b * NN + node];
    }
}

__global__ __launch_bounds__(256) void t_out(const float* __restrict__ src,
                                             float* __restrict__ dst) {
    int tid = blockIdx.x * 256 + (int)threadIdx.x;
    if (tid < NN * BATCH) {
        int b = tid / NN, node = tid - b * NN;
        dst[tid] = src[node * 64 + b];
    }
}

// -------- group0: img nodes (blocks 0..399) + out nodes (blocks 400..449) --------
__global__ __launch_bounds__(256) void g0_kernel(float* __restrict__ mt,
                                                 const float* __restrict__ J,
                                                 const float* __restrict__ H,
                                                 uint32_t k0, uint32_t k1) {
    __shared__ double red[4][64];
    int blk = blockIdx.x;
    if (blk < 400) {
        int tid = blk * 256 + (int)threadIdx.x;
        int g = __builtin_amdgcn_readfirstlane(tid >> 6);  // pixel, wave-uniform
        int b = (int)threadIdx.x & 63;                     // lane = batch
        int r = g / IMGW, c = g % IMGW;
        int pr_lo = (r >= 4) ? (r - 2) / 3 : 0;
        int pr_hi = r / 3; if (pr_hi > NPATCH - 1) pr_hi = NPATCH - 1;
        int pc_lo = (c >= 4) ? (c - 2) / 3 : 0;
        int pc_hi = c / 3; if (pc_hi > NPATCH - 1) pc_hi = NPATCH - 1;
        double acc = 0.0;
        for (int pr = pr_lo; pr <= pr_hi; ++pr) {
            for (int pc = pc_lo; pc <= pc_hi; ++pc) {
                int pos = (r - 3 * pr) * 5 + (c - 3 * pc);   // 0..24, wave-uniform
                int node0 = IMG_N + pr * NPATCH + pc;        // cnn node, f = 0
#pragma unroll
                for (int f = 0; f < 32; ++f) {
                    float w = jcnn(J, f, pos);               // L1-resident closure
                    acc += (double)w * (double)mt[(node0 + f * 144) * 64 + b];
                }
            }
        }
        float u = jax_uniform_pm1(k0, k1, (uint32_t)(b * G0SZ + g));
        mt[g * 64 + b] = gibbs_decide(acc, H[g], u);
    } else {
        int o = blk - 400;                        // out node 0..49
        int w = (int)threadIdx.x >> 6;            // wave: k-chunk
        int lane = (int)threadIdx.x & 63;         // lane = batch
        // out-node row is the CONTIGUOUS J_MLP column copy:
        const float* Jrow = J + (size_t)(IMG_N + CNN_N + o) * NN + IMG_N;
        double a0 = 0.0, a1 = 0.0;
        int k0i = w * 1152;
#pragma unroll 4
        for (int k = 0; k < 1152; k += 2) {
            a0 += (double)Jrow[k0i + k]     * (double)mt[(IMG_N + k0i + k) * 64 + lane];
            a1 += (double)Jrow[k0i + k + 1] * (double)mt[(IMG_N + k0i + k + 1) * 64 + lane];
        }
        red[w][lane] = a0 + a1;
        __syncthreads();
        if (w == 0) {
            double a = ((red[0][lane] + red[1][lane]) + red[2][lane]) + red[3][lane];
            float u = jax_uniform_pm1(k0, k1, (uint32_t)(lane * G0SZ + IMG_N + o));
            mt[(IMG_N + CNN_N + o) * 64 + lane] =
                gibbs_decide(a, H[IMG_N + CNN_N + o], u);
        }
    }
}

// -------- group1: cnn nodes, wave per cnode, lane = batch --------
__global__ __launch_bounds__(256) void g1_kernel(float* __restrict__ mt,
                                                 const float* __restrict__ J,
                                                 const float* __restrict__ H,
                                                 uint32_t k0, uint32_t k1) {
    int tid = blockIdx.x * 256 + (int)threadIdx.x;
    int cnode = __builtin_amdgcn_readfirstlane(tid >> 6);  // 0..4607
    int b = (int)threadIdx.x & 63;                         // lane = batch
    int f = cnode / 144;
    int p = cnode - f * 144;
    int pr = p / NPATCH, pc = p - pr * NPATCH;
    int r0 = pr * 3, c0 = pc * 3;
    double acc = 0.0;
#pragma unroll
    for (int a = 0; a < 5; ++a) {
        int rowbase = (r0 + a) * IMGW + c0;
#pragma unroll
        for (int bb = 0; bb < 5; ++bb) {
            float w = jcnn(J, f, a * 5 + bb);              // L1-resident closure
            acc += (double)w * (double)mt[(rowbase + bb) * 64 + b];
        }
    }
    const float* Jo = J + (size_t)(IMG_N + cnode) * NN + IMG_N + CNN_N;  // 50 contiguous
#pragma unroll 10
    for (int o = 0; o < OUT_N; ++o)
        acc += (double)Jo[o] * (double)mt[(IMG_N + CNN_N + o) * 64 + b];
    float u = jax_uniform_pm1(k0, k1, (uint32_t)(b * G1SZ + cnode));
    mt[(IMG_N + cnode) * 64 + b] = gibbs_decide(acc, H[IMG_N + cnode], u);
}

extern "C" void kernel_launch(void* const* d_in, const int* in_sizes, int n_in,
                              void* d_out, int out_size, void* d_ws, size_t ws_size,
                              hipStream_t stream) {
    const float* m_in = (const float*)d_in[0];
    const float* J    = (const float*)d_in[1];
    const float* H    = (const float*)d_in[2];
    float* m_out = (float*)d_out;
    float* mt    = (float*)d_ws;  // [NN][64] transposed spins (1.6 MB)

    const int TN = (NN * BATCH + 255) / 256;
    t_in<<<TN, 256, 0, stream>>>(m_in, mt);

    // partitionable key chain: keys = split(key(1),4): keys[i]=threefry((0,1),(0,i))
    uint32_t K[4][2];
    for (int i = 0; i < 4; ++i)
        tf2x32(0u, 1u, 0u, (uint32_t)i, K[i][0], K[i][1]);

    for (int s = 0; s < 4; ++s) {
        uint32_t k0a, k0b, k1a, k1b;
        tf2x32(K[s][0], K[s][1], 0u, 0u, k0a, k0b);  // k0 = split(keys[s])[0]
        tf2x32(K[s][0], K[s][1], 0u, 1u, k1a, k1b);  // k1 = split(keys[s])[1]
        g0_kernel<<<450, 256, 0, stream>>>(mt, J, H, k0a, k0b);
        g1_kernel<<<1152, 256, 0, stream>>>(mt, J, H, k1a, k1b);
    }

    t_out<<<TN, 256, 0, stream>>>(mt, m_out);
}